// Round 17
// baseline (151.430 us; speedup 1.0000x reference)
//
#include <hip/hip_runtime.h>
#include <hip/hip_bf16.h>
#include <hip/hip_fp16.h>
#include <math.h>

#define BB 2
#define DIMC 256
#define FF 4
#define HH 16
#define WW 16
#define GRP 4
#define CPG 64        // DIM/GROUPS
#define ODIM 128      // OFF_DIMS
#define PQ 1024       // F*H*W
#define PJ 128        // FD*HD*WD
#define NBG 8         // B*GROUPS
#define INNERC 512

typedef _Float16 f16x8 __attribute__((ext_vector_type(8)));
typedef _Float16 f16x4 __attribute__((ext_vector_type(4)));
typedef _Float16 f16x2 __attribute__((ext_vector_type(2)));
typedef float f32x4 __attribute__((ext_vector_type(4)));
typedef float f32x2 __attribute__((ext_vector_type(2)));

// ---- fused: q = grouped 1x1 conv (LDS-resident) -> depthwise conv + GELU
// Vectorized q-projection: 512 blocks (bg x 64 og-pairs, 2 out ch), 256 threads,
// each thread owns 4 consecutive p -> ONE float4 x-load per K-iter.
// (+ wo f32 -> f16 hi/lo conversion folded in)
__global__ __launch_bounds__(256) void k_qdw(
    const float* __restrict__ x, const float* __restrict__ wq,
    const float* __restrict__ dww, const float* __restrict__ dwb,
    const float* __restrict__ wo, _Float16* __restrict__ woH, _Float16* __restrict__ woL,
    float* __restrict__ q, float* __restrict__ act) {
    __shared__ float qs[1024 * 2];   // qs[p][cl] : 8 KB
    int og2 = blockIdx.x & 63, bg = blockIdx.x >> 6;
    int b = bg >> 2, g = bg & 3;
    int o0 = og2 * 2;
    int tid = threadIdx.x;           // 0..255

    {   // wo conversion: 512 blocks * 256 threads = 131072 = DIMC*INNERC
        int i = blockIdx.x * 256 + tid;
        float v = wo[i];
        _Float16 hh = (_Float16)v;
        woH[i] = hh;
        woL[i] = (_Float16)(v - (float)hh);
    }

    const float* xp = x + (size_t)(b * DIMC + g * CPG) * PQ;
    const float* wp = wq + (size_t)(g * ODIM + o0) * CPG;

    float accq[2][4] = {};           // [out k][p m]
    #pragma unroll 8
    for (int i = 0; i < CPG; ++i) {
        float w0v = wp[i];
        float w1v = wp[CPG + i];
        float4 xv = *(const float4*)&xp[(size_t)i * PQ + tid * 4];
        accq[0][0] += xv.x * w0v; accq[0][1] += xv.y * w0v;
        accq[0][2] += xv.z * w0v; accq[0][3] += xv.w * w0v;
        accq[1][0] += xv.x * w1v; accq[1][1] += xv.y * w1v;
        accq[1][2] += xv.z * w1v; accq[1][3] += xv.w * w1v;
    }
    // qs[p][cl]: thread's 8 values are contiguous at qs[tid*8]
    *(float4*)&qs[tid * 8]     = make_float4(accq[0][0], accq[1][0], accq[0][1], accq[1][1]);
    *(float4*)&qs[tid * 8 + 4] = make_float4(accq[0][2], accq[1][2], accq[0][3], accq[1][3]);
    #pragma unroll
    for (int k = 0; k < 2; ++k)
        *(float4*)&q[(size_t)(bg * ODIM + o0 + k) * PQ + tid * 4] =
            make_float4(accq[k][0], accq[k][1], accq[k][2], accq[k][3]);
    __syncthreads();

    {
        int cl = tid & 1, j = tid >> 1;   // 256 units = 128 j x 2 c
        int c = o0 + cl;
        int xo = j & 7, yo = (j >> 3) & 7, zo = j >> 6;
        const float* wd = dww + c * 64;
        float acc = dwb[c];
        #pragma unroll
        for (int kz = 0; kz < 4; ++kz) {
            int z = 2 * zo - 1 + kz;
            if (z < 0 || z >= FF) continue;
            #pragma unroll
            for (int ky = 0; ky < 4; ++ky) {
                int y = 2 * yo - 1 + ky;
                if (y < 0 || y >= HH) continue;
                #pragma unroll
                for (int kx = 0; kx < 4; ++kx) {
                    int xx = 2 * xo - 1 + kx;
                    if (xx < 0 || xx >= WW) continue;
                    acc += qs[((z * HH + y) * WW + xx) * 2 + cl] * wd[(kz * 4 + ky) * 4 + kx];
                }
            }
        }
        act[((size_t)bg * PJ + j) * ODIM + c] =
            0.5f * acc * (1.0f + erff(acc * 0.70710678118654752f));
    }
}

// ------- fused offsets -> grid -> trilinear sample -> k/v proj; 2 j's per block
__global__ __launch_bounds__(256) void k_kvf(
    const float* __restrict__ act, const float* __restrict__ pw,
    const float* __restrict__ x, const float* __restrict__ wk,
    const float* __restrict__ wv, float* __restrict__ gkv,
    _Float16* __restrict__ khT, _Float16* __restrict__ vhT) {
    __shared__ float red2[2][6];
    __shared__ float crd[2][3];
    __shared__ float kvs[2][64];
    int blk = blockIdx.x;            // bg*64 + jt
    int jt = blk & 63, bg = blk >> 6;
    int b = bg >> 2, g = bg & 3;
    int tid = threadIdx.x;
    int half = tid >> 7;
    int t = tid & 127;
    int j = jt * 2 + half;
    int wv_ = t >> 6;

    float val = act[((size_t)bg * PJ + j) * ODIM + t];
    float s0 = val * pw[t];
    float s1 = val * pw[ODIM + t];
    float s2 = val * pw[2 * ODIM + t];
    #pragma unroll
    for (int off = 32; off; off >>= 1) {
        s0 += __shfl_xor(s0, off);
        s1 += __shfl_xor(s1, off);
        s2 += __shfl_xor(s2, off);
    }
    if ((t & 63) == 0) {
        red2[half][wv_ * 3] = s0; red2[half][wv_ * 3 + 1] = s1; red2[half][wv_ * 3 + 2] = s2;
    }
    __syncthreads();
    if (t == 0) {
        s0 = red2[half][0] + red2[half][3];
        s1 = red2[half][1] + red2[half][4];
        s2 = red2[half][2] + red2[half][5];
        float xo = (float)(j & 7), yo = (float)((j >> 3) & 7), zo = (float)(j >> 6);
        float vf = zo + 2.f * tanhf(s0);
        float vh = yo + 2.f * tanhf(s1);
        float vw = xo + 2.f * tanhf(s2);
        float c0 = 2.f * vf - 1.f;
        float c1 = 2.f * vh / 7.f - 1.f;
        float c2 = 2.f * vw / 7.f - 1.f;
        crd[half][0] = c0; crd[half][1] = c1; crd[half][2] = c2;
        gkv[(bg * PJ + j) * 3 + 0] = c0;
        gkv[(bg * PJ + j) * 3 + 1] = c1;
        gkv[(bg * PJ + j) * 3 + 2] = c2;
    }
    __syncthreads();

    // BUG-COMPATIBLE: crd[0] (f-coord) -> x/W axis, crd[1] -> y/H, crd[2] (w) -> z/D.
    if (t < 64) {
        float ix = ((crd[half][0] + 1.f) * WW - 1.f) * 0.5f;
        float iy = ((crd[half][1] + 1.f) * HH - 1.f) * 0.5f;
        float iz = ((crd[half][2] + 1.f) * FF - 1.f) * 0.5f;
        float x0f = floorf(ix), y0f = floorf(iy), z0f = floorf(iz);
        float tx = ix - x0f, ty = iy - y0f, tz = iz - z0f;
        int x0 = (int)x0f, y0 = (int)y0f, z0 = (int)z0f;
        const float* vol = x + (size_t)(b * DIMC + g * CPG + t) * PQ;
        float acc = 0.f;
        #pragma unroll
        for (int dz = 0; dz < 2; ++dz) {
            int zc = z0 + dz;
            if (zc < 0 || zc >= FF) continue;
            float wz = dz ? tz : 1.f - tz;
            #pragma unroll
            for (int dy = 0; dy < 2; ++dy) {
                int yc = y0 + dy;
                if (yc < 0 || yc >= HH) continue;
                float wy = dy ? ty : 1.f - ty;
                #pragma unroll
                for (int dx = 0; dx < 2; ++dx) {
                    int xc = x0 + dx;
                    if (xc < 0 || xc >= WW) continue;
                    float wgt = wz * wy * (dx ? tx : 1.f - tx);
                    acc += vol[(zc * HH + yc) * WW + xc] * wgt;
                }
            }
        }
        kvs[half][t] = acc;
    }
    __syncthreads();

    const float* wkp = wk + (size_t)(g * ODIM + t) * CPG;
    const float* wvp = wv + (size_t)(g * ODIM + t) * CPG;
    float ak = 0.f, av = 0.f;
    #pragma unroll
    for (int i = 0; i < 64; i += 4) {
        float4 kv4 = *(const float4*)&kvs[half][i];
        float4 wk4 = *(const float4*)&wkp[i];
        float4 wv4 = *(const float4*)&wvp[i];
        ak += kv4.x * wk4.x + kv4.y * wk4.y + kv4.z * wk4.z + kv4.w * wk4.w;
        av += kv4.x * wv4.x + kv4.y * wv4.y + kv4.z * wv4.z + kv4.w * wv4.w;
    }
    {
        _Float16 khi = (_Float16)ak;
        khT[((size_t)(bg * 128 + j) * 2 + 0) * 128 + t] = khi;
        khT[((size_t)(bg * 128 + j) * 2 + 1) * 128 + t] = (_Float16)(ak - (float)khi);
        _Float16 vhi = (_Float16)av;
        vhT[((size_t)(bg * 128 + t) * 2 + 0) * 128 + j] = vhi;
        vhT[((size_t)(bg * 128 + t) * 2 + 1) * 128 + j] = (_Float16)(av - (float)vhi);
    }
}

// ---- fused CPB + QK^T + softmax + attn*V; 16 queries/block, 4 waves (r2 structure).
// Measured-best phase A: within a block, fq = it>>4 and hq = it&15 are constant,
// so t0,t1 depend only on j. base[j][d] = t0*w0a + t1*w0b + b0 is built ONCE per
// block (LDS, f16, pitch 72 -> 16B-aligned b128 frag reads), and the per-query
// ladder collapses to z = relu(fma(t2, w0c, base)) — 1 log + 1 FMA where there were 3.
// Epilogue uses the pipelined per-wave LDS scratch (NOT shfl chains: R8 showed
// CDNA __shfl = ds_bpermute on the LDS pipe, serialized by data deps — +13 µs).
__global__ __launch_bounds__(256) void k_cpa(
    const float* __restrict__ q, const _Float16* __restrict__ khT,
    const _Float16* __restrict__ vhT, const float* __restrict__ gkv,
    const float* __restrict__ w0, const float* __restrict__ b0,
    const float* __restrict__ w1, const float* __restrict__ b1,
    const float* __restrict__ w2, const float* __restrict__ b2,
    _Float16* __restrict__ outhH, _Float16* __restrict__ outhL) {
    __shared__ __align__(16) float tbuf[4 * 2176];      // 34816 B; phase-B alias below
    __shared__ __align__(16) float biasL[2 * 16 * 132]; // [head][il][j] pitch 132: 16.9 KB
    __shared__ __align__(16) _Float16 baseL[128 * 72];  // base[j][d] pitch 72: 18 KB
    __shared__ float smax[64];
    __shared__ float ssum[64];

    int blk = blockIdx.x;            // bg*64 + it
    int it = blk & 63, bg = blk >> 6;
    int b = bg >> 2, g = bg & 3;
    int tid = threadIdx.x;
    int w = tid >> 6, lane = tid & 63, col = lane & 15, quad = lane >> 4;

    // block-constant query coords (fq = it>>4, hq = it&15; only wq = il varies)
    float cq0c = 2.f * (float)(it >> 4) / 3.f - 1.f;
    float cq1c = 2.f * (float)(it & 15) / 15.f - 1.f;

    // ---------------- phase A0: build base[j][d] (once per block) ----------------
    {
        int j0_ = tid & 127, dh_ = tid >> 7;   // 2 threads per j, 32 d each
        float g0 = gkv[(bg * PJ + j0_) * 3 + 0];
        float g1 = gkv[(bg * PJ + j0_) * 3 + 1];
        float p0 = cq0c - g0, p1 = cq1c - g1;
        float t0 = copysignf(__logf(1.f + fabsf(p0)), p0);
        float t1 = copysignf(__logf(1.f + fabsf(p1)), p1);
        int d0_ = dh_ * 32;
        #pragma unroll
        for (int dd = 0; dd < 32; dd += 4) {
            int d = d0_ + dd;
            float4 wa = *(const float4*)&w0[d];
            float4 wb = *(const float4*)&w0[64 + d];
            float4 bb4 = *(const float4*)&b0[d];
            f16x4 pk4;
            pk4[0] = (_Float16)(t0 * wa.x + t1 * wb.x + bb4.x);
            pk4[1] = (_Float16)(t0 * wa.y + t1 * wb.y + bb4.y);
            pk4[2] = (_Float16)(t0 * wa.z + t1 * wb.z + bb4.z);
            pk4[3] = (_Float16)(t0 * wa.w + t1 * wb.w + bb4.w);
            *(f16x4*)&baseL[j0_ * 72 + d] = pk4;
        }
    }

    // W1 B-fragments in f16 (register-only; safe before the barrier)
    uint4 bfr[2][4];
    #pragma unroll
    for (int kc = 0; kc < 2; ++kc)
        #pragma unroll
        for (int nt = 0; nt < 4; ++nt) {
            int n = nt * 16 + col;
            int kbase = kc * 32 + quad * 8;
            unsigned int pk[4];
            #pragma unroll
            for (int p = 0; p < 4; ++p) {
                f16x2 hv = {(_Float16)w1[(kbase + 2 * p) * 64 + n],
                            (_Float16)w1[(kbase + 2 * p + 1) * 64 + n]};
                pk[p] = *(unsigned int*)&hv;
            }
            bfr[kc][nt] = make_uint4(pk[0], pk[1], pk[2], pk[3]);
        }

    // only the t2 row of w0 is needed per-lane now
    f16x2 w0c[2][4];
    #pragma unroll
    for (int kc = 0; kc < 2; ++kc) {
        int d0 = kc * 32 + quad * 8;
        #pragma unroll
        for (int pr = 0; pr < 4; ++pr)
            w0c[kc][pr] = (f16x2){(_Float16)w0[128 + d0 + 2 * pr],
                                  (_Float16)w0[128 + d0 + 2 * pr + 1]};
    }
    f16x2 zero2 = {(_Float16)0.f, (_Float16)0.f};

    float g2r[8];
    #pragma unroll
    for (int mtg = 0; mtg < 8; ++mtg)
        g2r[mtg] = gkv[(bg * PJ + mtg * 16 + col) * 3 + 2];

    float b1v[4]; f32x2 w2v[4];
    #pragma unroll
    for (int nt = 0; nt < 4; ++nt) {
        int jj = nt * 16 + col;
        b1v[nt] = b1[jj];
        w2v[nt] = *(const f32x2*)&w2[jj * 2];
    }
    f32x2 bias_b2 = *(const f32x2*)b2;
    f32x2* mytb = (f32x2*)&tbuf[w * 2176];

    __syncthreads();   // baseL ready

    // ---------------- phase A: CPB (barrier-free per wave) ----------------
    #pragma unroll 1
    for (int ii = 0; ii < 4; ++ii) {
        int il = w * 4 + ii;
        float cq2 = 2.f * (float)il / 15.f - 1.f;

        #pragma unroll 1
        for (int mh = 0; mh < 2; ++mh) {
            f16x2 t2h[4];
            #pragma unroll
            for (int mt = 0; mt < 4; ++mt) {
                float p2 = cq2 - g2r[mh * 4 + mt];
                float t2 = copysignf(__logf(1.f + fabsf(p2)), p2);
                _Float16 h2 = (_Float16)t2;
                t2h[mt] = (f16x2){h2, h2};
            }
            f32x4 acc[4][4] = {};
            #pragma unroll
            for (int kc = 0; kc < 2; ++kc) {
                #pragma unroll
                for (int mt = 0; mt < 4; ++mt) {
                    int jr = (mh * 4 + mt) * 16 + col;
                    f16x8 bse = *(const f16x8*)&baseL[jr * 72 + kc * 32 + quad * 8];
                    unsigned int pk[4];
                    #pragma unroll
                    for (int pr = 0; pr < 4; ++pr) {
                        f16x2 z = (f16x2){bse[2 * pr], bse[2 * pr + 1]}
                                  + t2h[mt] * w0c[kc][pr];
                        z = __builtin_elementwise_max(z, zero2);
                        pk[pr] = *(unsigned int*)&z;
                    }
                    uint4 afu = make_uint4(pk[0], pk[1], pk[2], pk[3]);
                    f16x8 af = *(f16x8*)&afu;
                    #pragma unroll
                    for (int nt = 0; nt < 4; ++nt)
                        acc[mt][nt] = __builtin_amdgcn_mfma_f32_16x16x32_f16(
                            af, *(f16x8*)&bfr[kc][nt], acc[mt][nt], 0, 0, 0);
                }
            }
            #pragma unroll
            for (int mt = 0; mt < 4; ++mt)
                #pragma unroll
                for (int reg = 0; reg < 4; ++reg) {
                    f32x2 pp = {0.f, 0.f};
                    #pragma unroll
                    for (int nt = 0; nt < 4; ++nt) {
                        float hv = fmaxf(acc[mt][nt][reg] + b1v[nt], 0.f);
                        pp += hv * w2v[nt];
                    }
                    mytb[(mt * 16 + quad * 4 + reg) * 17 + col] = pp;
                }
            f32x2 s = bias_b2;
            {
                const f32x2* pr2 = mytb + lane * 17;
                #pragma unroll
                for (int c = 0; c < 16; ++c) s += pr2[c];
            }
            int jl = mh * 64 + lane;
            biasL[il * 132 + jl] = s.x;            // head 0
            biasL[(16 + il) * 132 + jl] = s.y;     // head 1
        }
    }
    __syncthreads();   // phase A complete; tbuf now reusable

    // ---------------- phase B: attention for 16 queries (MFMA) ----------------
    _Float16* attFh = (_Float16*)tbuf;           // [2][16][136] : p~ hi
    _Float16* attFl = attFh + 4352;              // [2][16][136] : p~ lo
    _Float16* qsFh  = attFh + 8704;              // [16][136]    : q hi
    _Float16* qsFl  = attFh + 10880;             // [16][136]    : q lo

    {
        int o = tid & 127, hf = tid >> 7;
        const float* qp = q + (size_t)(bg * ODIM + o) * PQ + it * 16 + hf * 8;
        float4 qa = *(const float4*)qp;
        float4 qb = *(const float4*)(qp + 4);
        float vals[8] = {qa.x, qa.y, qa.z, qa.w, qb.x, qb.y, qb.z, qb.w};
        #pragma unroll
        for (int k = 0; k < 8; ++k) {
            float v = vals[k] * 0.125f;
            _Float16 vhi = (_Float16)v;
            qsFh[(hf * 8 + k) * 136 + o] = vhi;
            qsFl[(hf * 8 + k) * 136 + o] = (_Float16)(v - (float)vhi);
        }
    }
    __syncthreads();

    int h = w >> 1, jh = w & 1;      // wave role: head h, j-half jh

    // ---- QK^T (+bias) : C[i][j] for j in jh*64..jh*64+63
    f16x8 aqh[2], aql[2];
    #pragma unroll
    for (int kc = 0; kc < 2; ++kc) {
        aqh[kc] = *(f16x8*)&qsFh[col * 136 + h * 64 + kc * 32 + quad * 8];
        aql[kc] = *(f16x8*)&qsFl[col * 136 + h * 64 + kc * 32 + quad * 8];
    }
    f32x4 acc[4];
    #pragma unroll
    for (int jt = 0; jt < 4; ++jt) {
        int j0 = jh * 64 + jt * 16;
        #pragma unroll
        for (int r = 0; r < 4; ++r)
            acc[jt][r] = biasL[(h * 16 + quad * 4 + r) * 132 + j0 + col];
    }
    const _Float16* kbase = khT + (size_t)(bg * 128) * 256 + h * 64 + quad * 8;
    #pragma unroll
    for (int kc = 0; kc < 2; ++kc) {
        #pragma unroll
        for (int jt = 0; jt < 4; ++jt) {
            const _Float16* kp = kbase + (size_t)(jh * 64 + jt * 16 + col) * 256 + kc * 32;
            f16x8 bh = *(const f16x8*)kp;
            f16x8 bl = *(const f16x8*)(kp + 128);
            acc[jt] = __builtin_amdgcn_mfma_f32_16x16x32_f16(aqh[kc], bh, acc[jt], 0, 0, 0);
            acc[jt] = __builtin_amdgcn_mfma_f32_16x16x32_f16(aql[kc], bh, acc[jt], 0, 0, 0);
            acc[jt] = __builtin_amdgcn_mfma_f32_16x16x32_f16(aqh[kc], bl, acc[jt], 0, 0, 0);
        }
    }

    // ---- softmax over j=128 (two waves per head combine via LDS)
    float mrow[4];
    #pragma unroll
    for (int r = 0; r < 4; ++r) {
        float m = fmaxf(fmaxf(acc[0][r], acc[1][r]), fmaxf(acc[2][r], acc[3][r]));
        #pragma unroll
        for (int off = 1; off <= 8; off <<= 1) m = fmaxf(m, __shfl_xor(m, off));
        mrow[r] = m;
    }
    if (col == 0) {
        #pragma unroll
        for (int r = 0; r < 4; ++r) smax[(h * 2 + jh) * 16 + quad * 4 + r] = mrow[r];
    }
    __syncthreads();
    #pragma unroll
    for (int r = 0; r < 4; ++r)
        mrow[r] = fmaxf(smax[(h * 2) * 16 + quad * 4 + r],
                        smax[(h * 2 + 1) * 16 + quad * 4 + r]);

    float lrow[4] = {0.f, 0.f, 0.f, 0.f};
    #pragma unroll
    for (int jt = 0; jt < 4; ++jt) {
        int j0 = jh * 64 + jt * 16;
        #pragma unroll
        for (int r = 0; r < 4; ++r) {
            float p = __expf(acc[jt][r] - mrow[r]);
            lrow[r] += p;
            _Float16 phi = (_Float16)p;
            attFh[(h * 16 + quad * 4 + r) * 136 + j0 + col] = phi;
            attFl[(h * 16 + quad * 4 + r) * 136 + j0 + col] = (_Float16)(p - (float)phi);
        }
    }
    #pragma unroll
    for (int r = 0; r < 4; ++r) {
        float l = lrow[r];
        #pragma unroll
        for (int off = 1; off <= 8; off <<= 1) l += __shfl_xor(l, off);
        lrow[r] = l;
    }
    if (col == 0) {
        #pragma unroll
        for (int r = 0; r < 4; ++r) ssum[(h * 2 + jh) * 16 + quad * 4 + r] = lrow[r];
    }
    __syncthreads();

    // ---- attn * V : C[i][ch], wave covers ch-half jh of its head
    f16x8 pah[4], pal[4];
    #pragma unroll
    for (int kc = 0; kc < 4; ++kc) {
        pah[kc] = *(f16x8*)&attFh[(h * 16 + col) * 136 + kc * 32 + quad * 8];
        pal[kc] = *(f16x8*)&attFl[(h * 16 + col) * 136 + kc * 32 + quad * 8];
    }
    float rinv[4];
    #pragma unroll
    for (int r = 0; r < 4; ++r)
        rinv[r] = 1.f / (ssum[(h * 2) * 16 + quad * 4 + r] +
                         ssum[(h * 2 + 1) * 16 + quad * 4 + r]);

    f32x4 oacc[2] = {};
    int chl0 = jh * 32 + col;        // this wave's two ch tiles: chl0, chl0+16
    #pragma unroll
    for (int kc = 0; kc < 4; ++kc) {
        #pragma unroll
        for (int nt = 0; nt < 2; ++nt) {
            int chl = chl0 + nt * 16;
            const _Float16* vp = vhT + (size_t)(bg * 128 + h * 64 + chl) * 256 + kc * 32 + quad * 8;
            f16x8 vh8 = *(const f16x8*)vp;
            f16x8 vl8 = *(const f16x8*)(vp + 128);
            oacc[nt] = __builtin_amdgcn_mfma_f32_16x16x32_f16(pah[kc], vh8, oacc[nt], 0, 0, 0);
            oacc[nt] = __builtin_amdgcn_mfma_f32_16x16x32_f16(pal[kc], vh8, oacc[nt], 0, 0, 0);
            oacc[nt] = __builtin_amdgcn_mfma_f32_16x16x32_f16(pah[kc], vl8, oacc[nt], 0, 0, 0);
        }
    }
    #pragma unroll
    for (int nt = 0; nt < 2; ++nt) {
        int chl = chl0 + nt * 16;
        #pragma unroll
        for (int r = 0; r < 4; ++r) {
            float val = oacc[nt][r] * rinv[r];
            size_t idx = ((size_t)(b * PQ + it * 16 + quad * 4 + r)) * INNERC
                         + g * 128 + h * 64 + chl;
            _Float16 vhi = (_Float16)val;
            outhH[idx] = vhi;
            outhL[idx] = (_Float16)(val - (float)vhi);
        }
    }
}

// ---- final projection via compensated f16 MFMA. M=2048 (b*p), N=256 (o), K=512.
// R16 -> R17: 512 blocks (32 mtb x 16 ntb), ONE 16-o tile per wave -> 2 blocks/CU
// (was 1). Same K-order and per-tile accumulation; pure TLP increase.
__global__ __launch_bounds__(256) void k_out(
    const _Float16* __restrict__ outhH, const _Float16* __restrict__ outhL,
    const _Float16* __restrict__ woH, const _Float16* __restrict__ woL,
    const float* __restrict__ bo, float* __restrict__ out) {
    int blk = blockIdx.x;            // 32 mtb x 16 ntb
    int ntb = blk & 15, mtb = blk >> 4;
    int tid = threadIdx.x;
    int w = tid >> 6, lane = tid & 63, col = lane & 15, quad = lane >> 4;
    int m0 = mtb * 64 + w * 16;
    int o0 = ntb * 16;

    const _Float16* ahb = outhH + (size_t)(m0 + col) * INNERC + quad * 8;
    const _Float16* alb = outhL + (size_t)(m0 + col) * INNERC + quad * 8;

    f32x4 oacc = {};
    #pragma unroll 4
    for (int ks = 0; ks < 16; ++ks) {
        f16x8 ah = *(const f16x8*)(ahb + ks * 32);
        f16x8 al = *(const f16x8*)(alb + ks * 32);
        const _Float16* bp = woH + (size_t)(o0 + col) * INNERC + ks * 32 + quad * 8;
        const _Float16* lp = woL + (size_t)(o0 + col) * INNERC + ks * 32 + quad * 8;
        f16x8 bh = *(const f16x8*)bp;
        f16x8 bl = *(const f16x8*)lp;
        oacc = __builtin_amdgcn_mfma_f32_16x16x32_f16(ah, bh, oacc, 0, 0, 0);
        oacc = __builtin_amdgcn_mfma_f32_16x16x32_f16(al, bh, oacc, 0, 0, 0);
        oacc = __builtin_amdgcn_mfma_f32_16x16x32_f16(ah, bl, oacc, 0, 0, 0);
    }
    {
        int o = o0 + col;
        float bv = bo[o];
        int m = m0 + quad * 4;
        int bb = m >> 10, p = m & 1023;
        float4 st = make_float4(oacc[0] + bv, oacc[1] + bv, oacc[2] + bv, oacc[3] + bv);
        *(float4*)&out[((size_t)(bb * DIMC + o)) * PQ + p] = st;
    }
}

extern "C" void kernel_launch(void* const* d_in, const int* in_sizes, int n_in,
                              void* d_out, int out_size, void* d_ws, size_t ws_size,
                              hipStream_t stream) {
    const float* x   = (const float*)d_in[0];
    const float* wq  = (const float*)d_in[1];
    const float* wk  = (const float*)d_in[2];
    const float* wv  = (const float*)d_in[3];
    const float* dww = (const float*)d_in[4];
    const float* dwb = (const float*)d_in[5];
    const float* pw  = (const float*)d_in[6];
    const float* w0  = (const float*)d_in[7];
    const float* b0  = (const float*)d_in[8];
    const float* w1  = (const float*)d_in[9];
    const float* b1  = (const float*)d_in[10];
    const float* w2  = (const float*)d_in[11];
    const float* b2  = (const float*)d_in[12];
    const float* wo  = (const float*)d_in[13];
    const float* bo  = (const float*)d_in[14];
    float* out = (float*)d_out;

    float* ws_f  = (float*)d_ws;
    float* q     = ws_f;                              // 1048576 f32
    float* act   = q + 1048576;                       // 131072
    float* gkv   = act + 131072;                      // 3072
    _Float16* khT   = (_Float16*)(gkv + 3072);        // 262144 halves
    _Float16* vhT   = khT + 262144;                   // 262144 halves
    _Float16* outhH = vhT + 262144;                   // 1048576 halves
    _Float16* outhL = outhH + 1048576;                // 1048576 halves
    _Float16* woH   = outhL + 1048576;                // 131072 halves
    _Float16* woL   = woH + 131072;                   // 131072 halves

    k_qdw<<<512, 256, 0, stream>>>(x, wq, dww, dwb, wo, woH, woL, q, act);
    k_kvf<<<512, 256, 0, stream>>>(act, pw, x, wk, wv, gkv, khT, vhT);
    k_cpa<<<512, 256, 0, stream>>>(q, khT, vhT, gkv, w0, b0, w1, b1, w2, b2, outhH, outhL);
    k_out<<<512, 256, 0, stream>>>(outhH, outhL, woH, woL, bo, out);
}

// Round 20
// 146.432 us; speedup vs baseline: 1.0341x; 1.0341x over previous
//
#include <hip/hip_runtime.h>
#include <hip/hip_bf16.h>
#include <hip/hip_fp16.h>
#include <math.h>

#define BB 2
#define DIMC 256
#define FF 4
#define HH 16
#define WW 16
#define GRP 4
#define CPG 64        // DIM/GROUPS
#define ODIM 128      // OFF_DIMS
#define PQ 1024       // F*H*W
#define PJ 128        // FD*HD*WD
#define NBG 8         // B*GROUPS
#define INNERC 512

typedef _Float16 f16x8 __attribute__((ext_vector_type(8)));
typedef _Float16 f16x4 __attribute__((ext_vector_type(4)));
typedef _Float16 f16x2 __attribute__((ext_vector_type(2)));
typedef float f32x4 __attribute__((ext_vector_type(4)));
typedef float f32x2 __attribute__((ext_vector_type(2)));

// ---- fused: q = grouped 1x1 conv (LDS-resident) -> depthwise conv + GELU
// Vectorized q-projection: 512 blocks (bg x 64 og-pairs, 2 out ch), 256 threads,
// each thread owns 4 consecutive p -> ONE float4 x-load per K-iter.
// (+ wo f32 -> f16 hi/lo conversion folded in)
__global__ __launch_bounds__(256) void k_qdw(
    const float* __restrict__ x, const float* __restrict__ wq,
    const float* __restrict__ dww, const float* __restrict__ dwb,
    const float* __restrict__ wo, _Float16* __restrict__ woH, _Float16* __restrict__ woL,
    float* __restrict__ q, float* __restrict__ act) {
    __shared__ float qs[1024 * 2];   // qs[p][cl] : 8 KB
    int og2 = blockIdx.x & 63, bg = blockIdx.x >> 6;
    int b = bg >> 2, g = bg & 3;
    int o0 = og2 * 2;
    int tid = threadIdx.x;           // 0..255

    {   // wo conversion: 512 blocks * 256 threads = 131072 = DIMC*INNERC
        int i = blockIdx.x * 256 + tid;
        float v = wo[i];
        _Float16 hh = (_Float16)v;
        woH[i] = hh;
        woL[i] = (_Float16)(v - (float)hh);
    }

    const float* xp = x + (size_t)(b * DIMC + g * CPG) * PQ;
    const float* wp = wq + (size_t)(g * ODIM + o0) * CPG;

    float accq[2][4] = {};           // [out k][p m]
    #pragma unroll 8
    for (int i = 0; i < CPG; ++i) {
        float w0v = wp[i];
        float w1v = wp[CPG + i];
        float4 xv = *(const float4*)&xp[(size_t)i * PQ + tid * 4];
        accq[0][0] += xv.x * w0v; accq[0][1] += xv.y * w0v;
        accq[0][2] += xv.z * w0v; accq[0][3] += xv.w * w0v;
        accq[1][0] += xv.x * w1v; accq[1][1] += xv.y * w1v;
        accq[1][2] += xv.z * w1v; accq[1][3] += xv.w * w1v;
    }
    // qs[p][cl]: thread's 8 values are contiguous at qs[tid*8]
    *(float4*)&qs[tid * 8]     = make_float4(accq[0][0], accq[1][0], accq[0][1], accq[1][1]);
    *(float4*)&qs[tid * 8 + 4] = make_float4(accq[0][2], accq[1][2], accq[0][3], accq[1][3]);
    #pragma unroll
    for (int k = 0; k < 2; ++k)
        *(float4*)&q[(size_t)(bg * ODIM + o0 + k) * PQ + tid * 4] =
            make_float4(accq[k][0], accq[k][1], accq[k][2], accq[k][3]);
    __syncthreads();

    {
        int cl = tid & 1, j = tid >> 1;   // 256 units = 128 j x 2 c
        int c = o0 + cl;
        int xo = j & 7, yo = (j >> 3) & 7, zo = j >> 6;
        const float* wd = dww + c * 64;
        float acc = dwb[c];
        #pragma unroll
        for (int kz = 0; kz < 4; ++kz) {
            int z = 2 * zo - 1 + kz;
            if (z < 0 || z >= FF) continue;
            #pragma unroll
            for (int ky = 0; ky < 4; ++ky) {
                int y = 2 * yo - 1 + ky;
                if (y < 0 || y >= HH) continue;
                #pragma unroll
                for (int kx = 0; kx < 4; ++kx) {
                    int xx = 2 * xo - 1 + kx;
                    if (xx < 0 || xx >= WW) continue;
                    acc += qs[((z * HH + y) * WW + xx) * 2 + cl] * wd[(kz * 4 + ky) * 4 + kx];
                }
            }
        }
        act[((size_t)bg * PJ + j) * ODIM + c] =
            0.5f * acc * (1.0f + erff(acc * 0.70710678118654752f));
    }
}

// ------- fused offsets -> grid -> trilinear sample -> k/v proj; 2 j's per block
__global__ __launch_bounds__(256) void k_kvf(
    const float* __restrict__ act, const float* __restrict__ pw,
    const float* __restrict__ x, const float* __restrict__ wk,
    const float* __restrict__ wv, float* __restrict__ gkv,
    _Float16* __restrict__ khT, _Float16* __restrict__ vhT) {
    __shared__ float red2[2][6];
    __shared__ float crd[2][3];
    __shared__ float kvs[2][64];
    int blk = blockIdx.x;            // bg*64 + jt
    int jt = blk & 63, bg = blk >> 6;
    int b = bg >> 2, g = bg & 3;
    int tid = threadIdx.x;
    int half = tid >> 7;
    int t = tid & 127;
    int j = jt * 2 + half;
    int wv_ = t >> 6;

    float val = act[((size_t)bg * PJ + j) * ODIM + t];
    float s0 = val * pw[t];
    float s1 = val * pw[ODIM + t];
    float s2 = val * pw[2 * ODIM + t];
    #pragma unroll
    for (int off = 32; off; off >>= 1) {
        s0 += __shfl_xor(s0, off);
        s1 += __shfl_xor(s1, off);
        s2 += __shfl_xor(s2, off);
    }
    if ((t & 63) == 0) {
        red2[half][wv_ * 3] = s0; red2[half][wv_ * 3 + 1] = s1; red2[half][wv_ * 3 + 2] = s2;
    }
    __syncthreads();
    if (t == 0) {
        s0 = red2[half][0] + red2[half][3];
        s1 = red2[half][1] + red2[half][4];
        s2 = red2[half][2] + red2[half][5];
        float xo = (float)(j & 7), yo = (float)((j >> 3) & 7), zo = (float)(j >> 6);
        float vf = zo + 2.f * tanhf(s0);
        float vh = yo + 2.f * tanhf(s1);
        float vw = xo + 2.f * tanhf(s2);
        float c0 = 2.f * vf - 1.f;
        float c1 = 2.f * vh / 7.f - 1.f;
        float c2 = 2.f * vw / 7.f - 1.f;
        crd[half][0] = c0; crd[half][1] = c1; crd[half][2] = c2;
        gkv[(bg * PJ + j) * 3 + 0] = c0;
        gkv[(bg * PJ + j) * 3 + 1] = c1;
        gkv[(bg * PJ + j) * 3 + 2] = c2;
    }
    __syncthreads();

    // BUG-COMPATIBLE: crd[0] (f-coord) -> x/W axis, crd[1] -> y/H, crd[2] (w) -> z/D.
    if (t < 64) {
        float ix = ((crd[half][0] + 1.f) * WW - 1.f) * 0.5f;
        float iy = ((crd[half][1] + 1.f) * HH - 1.f) * 0.5f;
        float iz = ((crd[half][2] + 1.f) * FF - 1.f) * 0.5f;
        float x0f = floorf(ix), y0f = floorf(iy), z0f = floorf(iz);
        float tx = ix - x0f, ty = iy - y0f, tz = iz - z0f;
        int x0 = (int)x0f, y0 = (int)y0f, z0 = (int)z0f;
        const float* vol = x + (size_t)(b * DIMC + g * CPG + t) * PQ;
        float acc = 0.f;
        #pragma unroll
        for (int dz = 0; dz < 2; ++dz) {
            int zc = z0 + dz;
            if (zc < 0 || zc >= FF) continue;
            float wz = dz ? tz : 1.f - tz;
            #pragma unroll
            for (int dy = 0; dy < 2; ++dy) {
                int yc = y0 + dy;
                if (yc < 0 || yc >= HH) continue;
                float wy = dy ? ty : 1.f - ty;
                #pragma unroll
                for (int dx = 0; dx < 2; ++dx) {
                    int xc = x0 + dx;
                    if (xc < 0 || xc >= WW) continue;
                    float wgt = wz * wy * (dx ? tx : 1.f - tx);
                    acc += vol[(zc * HH + yc) * WW + xc] * wgt;
                }
            }
        }
        kvs[half][t] = acc;
    }
    __syncthreads();

    const float* wkp = wk + (size_t)(g * ODIM + t) * CPG;
    const float* wvp = wv + (size_t)(g * ODIM + t) * CPG;
    float ak = 0.f, av = 0.f;
    #pragma unroll
    for (int i = 0; i < 64; i += 4) {
        float4 kv4 = *(const float4*)&kvs[half][i];
        float4 wk4 = *(const float4*)&wkp[i];
        float4 wv4 = *(const float4*)&wvp[i];
        ak += kv4.x * wk4.x + kv4.y * wk4.y + kv4.z * wk4.z + kv4.w * wk4.w;
        av += kv4.x * wv4.x + kv4.y * wv4.y + kv4.z * wv4.z + kv4.w * wv4.w;
    }
    {
        _Float16 khi = (_Float16)ak;
        khT[((size_t)(bg * 128 + j) * 2 + 0) * 128 + t] = khi;
        khT[((size_t)(bg * 128 + j) * 2 + 1) * 128 + t] = (_Float16)(ak - (float)khi);
        _Float16 vhi = (_Float16)av;
        vhT[((size_t)(bg * 128 + t) * 2 + 0) * 128 + j] = vhi;
        vhT[((size_t)(bg * 128 + t) * 2 + 1) * 128 + j] = (_Float16)(av - (float)vhi);
    }
}

// ---- fused CPB + QK^T + softmax + attn*V; 16 queries/block, 4 waves (r2 structure).
// Measured-best phase A: within a block, fq = it>>4 and hq = it&15 are constant,
// so t0,t1 depend only on j. base[j][d] = t0*w0a + t1*w0b + b0 is built ONCE per
// block (LDS, f16, pitch 72 -> 16B-aligned b128 frag reads), and the per-query
// ladder collapses to z = relu(fma(t2, w0c, base)) — 1 log + 1 FMA where there were 3.
// Epilogue uses the pipelined per-wave LDS scratch (NOT shfl chains: R8 showed
// CDNA __shfl = ds_bpermute on the LDS pipe, serialized by data deps — +13 µs).
__global__ __launch_bounds__(256) void k_cpa(
    const float* __restrict__ q, const _Float16* __restrict__ khT,
    const _Float16* __restrict__ vhT, const float* __restrict__ gkv,
    const float* __restrict__ w0, const float* __restrict__ b0,
    const float* __restrict__ w1, const float* __restrict__ b1,
    const float* __restrict__ w2, const float* __restrict__ b2,
    _Float16* __restrict__ outhH, _Float16* __restrict__ outhL) {
    __shared__ __align__(16) float tbuf[4 * 2176];      // 34816 B; phase-B alias below
    __shared__ __align__(16) float biasL[2 * 16 * 132]; // [head][il][j] pitch 132: 16.9 KB
    __shared__ __align__(16) _Float16 baseL[128 * 72];  // base[j][d] pitch 72: 18 KB
    __shared__ float smax[64];
    __shared__ float ssum[64];

    int blk = blockIdx.x;            // bg*64 + it
    int it = blk & 63, bg = blk >> 6;
    int b = bg >> 2, g = bg & 3;
    int tid = threadIdx.x;
    int w = tid >> 6, lane = tid & 63, col = lane & 15, quad = lane >> 4;

    // block-constant query coords (fq = it>>4, hq = it&15; only wq = il varies)
    float cq0c = 2.f * (float)(it >> 4) / 3.f - 1.f;
    float cq1c = 2.f * (float)(it & 15) / 15.f - 1.f;

    // ---------------- phase A0: build base[j][d] (once per block) ----------------
    {
        int j0_ = tid & 127, dh_ = tid >> 7;   // 2 threads per j, 32 d each
        float g0 = gkv[(bg * PJ + j0_) * 3 + 0];
        float g1 = gkv[(bg * PJ + j0_) * 3 + 1];
        float p0 = cq0c - g0, p1 = cq1c - g1;
        float t0 = copysignf(__logf(1.f + fabsf(p0)), p0);
        float t1 = copysignf(__logf(1.f + fabsf(p1)), p1);
        int d0_ = dh_ * 32;
        #pragma unroll
        for (int dd = 0; dd < 32; dd += 4) {
            int d = d0_ + dd;
            float4 wa = *(const float4*)&w0[d];
            float4 wb = *(const float4*)&w0[64 + d];
            float4 bb4 = *(const float4*)&b0[d];
            f16x4 pk4;
            pk4[0] = (_Float16)(t0 * wa.x + t1 * wb.x + bb4.x);
            pk4[1] = (_Float16)(t0 * wa.y + t1 * wb.y + bb4.y);
            pk4[2] = (_Float16)(t0 * wa.z + t1 * wb.z + bb4.z);
            pk4[3] = (_Float16)(t0 * wa.w + t1 * wb.w + bb4.w);
            *(f16x4*)&baseL[j0_ * 72 + d] = pk4;
        }
    }

    // W1 B-fragments in f16 (register-only; safe before the barrier)
    uint4 bfr[2][4];
    #pragma unroll
    for (int kc = 0; kc < 2; ++kc)
        #pragma unroll
        for (int nt = 0; nt < 4; ++nt) {
            int n = nt * 16 + col;
            int kbase = kc * 32 + quad * 8;
            unsigned int pk[4];
            #pragma unroll
            for (int p = 0; p < 4; ++p) {
                f16x2 hv = {(_Float16)w1[(kbase + 2 * p) * 64 + n],
                            (_Float16)w1[(kbase + 2 * p + 1) * 64 + n]};
                pk[p] = *(unsigned int*)&hv;
            }
            bfr[kc][nt] = make_uint4(pk[0], pk[1], pk[2], pk[3]);
        }

    // only the t2 row of w0 is needed per-lane now
    f16x2 w0c[2][4];
    #pragma unroll
    for (int kc = 0; kc < 2; ++kc) {
        int d0 = kc * 32 + quad * 8;
        #pragma unroll
        for (int pr = 0; pr < 4; ++pr)
            w0c[kc][pr] = (f16x2){(_Float16)w0[128 + d0 + 2 * pr],
                                  (_Float16)w0[128 + d0 + 2 * pr + 1]};
    }
    f16x2 zero2 = {(_Float16)0.f, (_Float16)0.f};

    float g2r[8];
    #pragma unroll
    for (int mtg = 0; mtg < 8; ++mtg)
        g2r[mtg] = gkv[(bg * PJ + mtg * 16 + col) * 3 + 2];

    float b1v[4]; f32x2 w2v[4];
    #pragma unroll
    for (int nt = 0; nt < 4; ++nt) {
        int jj = nt * 16 + col;
        b1v[nt] = b1[jj];
        w2v[nt] = *(const f32x2*)&w2[jj * 2];
    }
    f32x2 bias_b2 = *(const f32x2*)b2;
    f32x2* mytb = (f32x2*)&tbuf[w * 2176];

    __syncthreads();   // baseL ready

    // ---------------- phase A: CPB (barrier-free per wave) ----------------
    #pragma unroll 1
    for (int ii = 0; ii < 4; ++ii) {
        int il = w * 4 + ii;
        float cq2 = 2.f * (float)il / 15.f - 1.f;

        #pragma unroll 1
        for (int mh = 0; mh < 2; ++mh) {
            f16x2 t2h[4];
            #pragma unroll
            for (int mt = 0; mt < 4; ++mt) {
                float p2 = cq2 - g2r[mh * 4 + mt];
                float t2 = copysignf(__logf(1.f + fabsf(p2)), p2);
                _Float16 h2 = (_Float16)t2;
                t2h[mt] = (f16x2){h2, h2};
            }
            f32x4 acc[4][4] = {};
            #pragma unroll
            for (int kc = 0; kc < 2; ++kc) {
                #pragma unroll
                for (int mt = 0; mt < 4; ++mt) {
                    int jr = (mh * 4 + mt) * 16 + col;
                    f16x8 bse = *(const f16x8*)&baseL[jr * 72 + kc * 32 + quad * 8];
                    unsigned int pk[4];
                    #pragma unroll
                    for (int pr = 0; pr < 4; ++pr) {
                        f16x2 z = (f16x2){bse[2 * pr], bse[2 * pr + 1]}
                                  + t2h[mt] * w0c[kc][pr];
                        z = __builtin_elementwise_max(z, zero2);
                        pk[pr] = *(unsigned int*)&z;
                    }
                    uint4 afu = make_uint4(pk[0], pk[1], pk[2], pk[3]);
                    f16x8 af = *(f16x8*)&afu;
                    #pragma unroll
                    for (int nt = 0; nt < 4; ++nt)
                        acc[mt][nt] = __builtin_amdgcn_mfma_f32_16x16x32_f16(
                            af, *(f16x8*)&bfr[kc][nt], acc[mt][nt], 0, 0, 0);
                }
            }
            #pragma unroll
            for (int mt = 0; mt < 4; ++mt)
                #pragma unroll
                for (int reg = 0; reg < 4; ++reg) {
                    f32x2 pp = {0.f, 0.f};
                    #pragma unroll
                    for (int nt = 0; nt < 4; ++nt) {
                        float hv = fmaxf(acc[mt][nt][reg] + b1v[nt], 0.f);
                        pp += hv * w2v[nt];
                    }
                    mytb[(mt * 16 + quad * 4 + reg) * 17 + col] = pp;
                }
            f32x2 s = bias_b2;
            {
                const f32x2* pr2 = mytb + lane * 17;
                #pragma unroll
                for (int c = 0; c < 16; ++c) s += pr2[c];
            }
            int jl = mh * 64 + lane;
            biasL[il * 132 + jl] = s.x;            // head 0
            biasL[(16 + il) * 132 + jl] = s.y;     // head 1
        }
    }
    __syncthreads();   // phase A complete; tbuf now reusable

    // ---------------- phase B: attention for 16 queries (MFMA) ----------------
    _Float16* attFh = (_Float16*)tbuf;           // [2][16][136] : p~ hi
    _Float16* attFl = attFh + 4352;              // [2][16][136] : p~ lo
    _Float16* qsFh  = attFh + 8704;              // [16][136]    : q hi
    _Float16* qsFl  = attFh + 10880;             // [16][136]    : q lo

    {
        int o = tid & 127, hf = tid >> 7;
        const float* qp = q + (size_t)(bg * ODIM + o) * PQ + it * 16 + hf * 8;
        float4 qa = *(const float4*)qp;
        float4 qb = *(const float4*)(qp + 4);
        float vals[8] = {qa.x, qa.y, qa.z, qa.w, qb.x, qb.y, qb.z, qb.w};
        #pragma unroll
        for (int k = 0; k < 8; ++k) {
            float v = vals[k] * 0.125f;
            _Float16 vhi = (_Float16)v;
            qsFh[(hf * 8 + k) * 136 + o] = vhi;
            qsFl[(hf * 8 + k) * 136 + o] = (_Float16)(v - (float)vhi);
        }
    }
    __syncthreads();

    int h = w >> 1, jh = w & 1;      // wave role: head h, j-half jh

    // ---- QK^T (+bias) : C[i][j] for j in jh*64..jh*64+63
    f16x8 aqh[2], aql[2];
    #pragma unroll
    for (int kc = 0; kc < 2; ++kc) {
        aqh[kc] = *(f16x8*)&qsFh[col * 136 + h * 64 + kc * 32 + quad * 8];
        aql[kc] = *(f16x8*)&qsFl[col * 136 + h * 64 + kc * 32 + quad * 8];
    }
    f32x4 acc[4];
    #pragma unroll
    for (int jt = 0; jt < 4; ++jt) {
        int j0 = jh * 64 + jt * 16;
        #pragma unroll
        for (int r = 0; r < 4; ++r)
            acc[jt][r] = biasL[(h * 16 + quad * 4 + r) * 132 + j0 + col];
    }
    const _Float16* kbase = khT + (size_t)(bg * 128) * 256 + h * 64 + quad * 8;
    #pragma unroll
    for (int kc = 0; kc < 2; ++kc) {
        #pragma unroll
        for (int jt = 0; jt < 4; ++jt) {
            const _Float16* kp = kbase + (size_t)(jh * 64 + jt * 16 + col) * 256 + kc * 32;
            f16x8 bh = *(const f16x8*)kp;
            f16x8 bl = *(const f16x8*)(kp + 128);
            acc[jt] = __builtin_amdgcn_mfma_f32_16x16x32_f16(aqh[kc], bh, acc[jt], 0, 0, 0);
            acc[jt] = __builtin_amdgcn_mfma_f32_16x16x32_f16(aql[kc], bh, acc[jt], 0, 0, 0);
            acc[jt] = __builtin_amdgcn_mfma_f32_16x16x32_f16(aqh[kc], bl, acc[jt], 0, 0, 0);
        }
    }

    // ---- softmax over j=128 (two waves per head combine via LDS)
    float mrow[4];
    #pragma unroll
    for (int r = 0; r < 4; ++r) {
        float m = fmaxf(fmaxf(acc[0][r], acc[1][r]), fmaxf(acc[2][r], acc[3][r]));
        #pragma unroll
        for (int off = 1; off <= 8; off <<= 1) m = fmaxf(m, __shfl_xor(m, off));
        mrow[r] = m;
    }
    if (col == 0) {
        #pragma unroll
        for (int r = 0; r < 4; ++r) smax[(h * 2 + jh) * 16 + quad * 4 + r] = mrow[r];
    }
    __syncthreads();
    #pragma unroll
    for (int r = 0; r < 4; ++r)
        mrow[r] = fmaxf(smax[(h * 2) * 16 + quad * 4 + r],
                        smax[(h * 2 + 1) * 16 + quad * 4 + r]);

    float lrow[4] = {0.f, 0.f, 0.f, 0.f};
    #pragma unroll
    for (int jt = 0; jt < 4; ++jt) {
        int j0 = jh * 64 + jt * 16;
        #pragma unroll
        for (int r = 0; r < 4; ++r) {
            float p = __expf(acc[jt][r] - mrow[r]);
            lrow[r] += p;
            _Float16 phi = (_Float16)p;
            attFh[(h * 16 + quad * 4 + r) * 136 + j0 + col] = phi;
            attFl[(h * 16 + quad * 4 + r) * 136 + j0 + col] = (_Float16)(p - (float)phi);
        }
    }
    #pragma unroll
    for (int r = 0; r < 4; ++r) {
        float l = lrow[r];
        #pragma unroll
        for (int off = 1; off <= 8; off <<= 1) l += __shfl_xor(l, off);
        lrow[r] = l;
    }
    if (col == 0) {
        #pragma unroll
        for (int r = 0; r < 4; ++r) ssum[(h * 2 + jh) * 16 + quad * 4 + r] = lrow[r];
    }
    __syncthreads();

    // ---- attn * V : C[i][ch], wave covers ch-half jh of its head
    f16x8 pah[4], pal[4];
    #pragma unroll
    for (int kc = 0; kc < 4; ++kc) {
        pah[kc] = *(f16x8*)&attFh[(h * 16 + col) * 136 + kc * 32 + quad * 8];
        pal[kc] = *(f16x8*)&attFl[(h * 16 + col) * 136 + kc * 32 + quad * 8];
    }
    float rinv[4];
    #pragma unroll
    for (int r = 0; r < 4; ++r)
        rinv[r] = 1.f / (ssum[(h * 2) * 16 + quad * 4 + r] +
                         ssum[(h * 2 + 1) * 16 + quad * 4 + r]);

    f32x4 oacc[2] = {};
    int chl0 = jh * 32 + col;        // this wave's two ch tiles: chl0, chl0+16
    #pragma unroll
    for (int kc = 0; kc < 4; ++kc) {
        #pragma unroll
        for (int nt = 0; nt < 2; ++nt) {
            int chl = chl0 + nt * 16;
            const _Float16* vp = vhT + (size_t)(bg * 128 + h * 64 + chl) * 256 + kc * 32 + quad * 8;
            f16x8 vh8 = *(const f16x8*)vp;
            f16x8 vl8 = *(const f16x8*)(vp + 128);
            oacc[nt] = __builtin_amdgcn_mfma_f32_16x16x32_f16(pah[kc], vh8, oacc[nt], 0, 0, 0);
            oacc[nt] = __builtin_amdgcn_mfma_f32_16x16x32_f16(pal[kc], vh8, oacc[nt], 0, 0, 0);
            oacc[nt] = __builtin_amdgcn_mfma_f32_16x16x32_f16(pah[kc], vl8, oacc[nt], 0, 0, 0);
        }
    }
    #pragma unroll
    for (int nt = 0; nt < 2; ++nt) {
        int chl = chl0 + nt * 16;
        #pragma unroll
        for (int r = 0; r < 4; ++r) {
            float val = oacc[nt][r] * rinv[r];
            size_t idx = ((size_t)(b * PQ + it * 16 + quad * 4 + r)) * INNERC
                         + g * 128 + h * 64 + chl;
            _Float16 vhi = (_Float16)val;
            outhH[idx] = vhi;
            outhL[idx] = (_Float16)(val - (float)vhi);
        }
    }
}

// ---- final projection via compensated f16 MFMA. M=2048 (b*p), N=256 (o), K=512.
// Measured-best form: 256 blocks (32 mtb x 8 ntb), 2 o-tiles per wave — the
// A-fragment reuse (ah/al loaded once, used for both B tiles) beats the 512-block
// split (R17: +4.2 µs from doubled outh traffic at halved arithmetic intensity).
__global__ __launch_bounds__(256) void k_out(
    const _Float16* __restrict__ outhH, const _Float16* __restrict__ outhL,
    const _Float16* __restrict__ woH, const _Float16* __restrict__ woL,
    const float* __restrict__ bo, float* __restrict__ out) {
    int blk = blockIdx.x;            // 32 mtb x 8 ntb
    int ntb = blk & 7, mtb = blk >> 3;
    int tid = threadIdx.x;
    int w = tid >> 6, lane = tid & 63, col = lane & 15, quad = lane >> 4;
    int m0 = mtb * 64 + w * 16;
    int o0 = ntb * 32;

    const _Float16* ahb = outhH + (size_t)(m0 + col) * INNERC + quad * 8;
    const _Float16* alb = outhL + (size_t)(m0 + col) * INNERC + quad * 8;

    f32x4 oacc[2] = {};
    #pragma unroll 4
    for (int ks = 0; ks < 16; ++ks) {
        f16x8 ah = *(const f16x8*)(ahb + ks * 32);
        f16x8 al = *(const f16x8*)(alb + ks * 32);
        #pragma unroll
        for (int nt = 0; nt < 2; ++nt) {
            const _Float16* bp = woH + (size_t)(o0 + nt * 16 + col) * INNERC + ks * 32 + quad * 8;
            const _Float16* lp = woL + (size_t)(o0 + nt * 16 + col) * INNERC + ks * 32 + quad * 8;
            f16x8 bh = *(const f16x8*)bp;
            f16x8 bl = *(const f16x8*)lp;
            oacc[nt] = __builtin_amdgcn_mfma_f32_16x16x32_f16(ah, bh, oacc[nt], 0, 0, 0);
            oacc[nt] = __builtin_amdgcn_mfma_f32_16x16x32_f16(al, bh, oacc[nt], 0, 0, 0);
            oacc[nt] = __builtin_amdgcn_mfma_f32_16x16x32_f16(ah, bl, oacc[nt], 0, 0, 0);
        }
    }
    #pragma unroll
    for (int nt = 0; nt < 2; ++nt) {
        int o = o0 + nt * 16 + col;
        float bv = bo[o];
        int m = m0 + quad * 4;
        int bb = m >> 10, p = m & 1023;
        float4 st = make_float4(oacc[nt][0] + bv, oacc[nt][1] + bv,
                                oacc[nt][2] + bv, oacc[nt][3] + bv);
        *(float4*)&out[((size_t)(bb * DIMC + o)) * PQ + p] = st;
    }
}

extern "C" void kernel_launch(void* const* d_in, const int* in_sizes, int n_in,
                              void* d_out, int out_size, void* d_ws, size_t ws_size,
                              hipStream_t stream) {
    const float* x   = (const float*)d_in[0];
    const float* wq  = (const float*)d_in[1];
    const float* wk  = (const float*)d_in[2];
    const float* wv  = (const float*)d_in[3];
    const float* dww = (const float*)d_in[4];
    const float* dwb = (const float*)d_in[5];
    const float* pw  = (const float*)d_in[6];
    const float* w0  = (const float*)d_in[7];
    const float* b0  = (const float*)d_in[8];
    const float* w1  = (const float*)d_in[9];
    const float* b1  = (const float*)d_in[10];
    const float* w2  = (const float*)d_in[11];
    const float* b2  = (const float*)d_in[12];
    const float* wo  = (const float*)d_in[13];
    const float* bo  = (const float*)d_in[14];
    float* out = (float*)d_out;

    float* ws_f  = (float*)d_ws;
    float* q     = ws_f;                              // 1048576 f32
    float* act   = q + 1048576;                       // 131072
    float* gkv   = act + 131072;                      // 3072
    _Float16* khT   = (_Float16*)(gkv + 3072);        // 262144 halves
    _Float16* vhT   = khT + 262144;                   // 262144 halves
    _Float16* outhH = vhT + 262144;                   // 1048576 halves
    _Float16* outhL = outhH + 1048576;                // 1048576 halves
    _Float16* woH   = outhL + 1048576;                // 131072 halves
    _Float16* woL   = woH + 131072;                   // 131072 halves

    k_qdw<<<512, 256, 0, stream>>>(x, wq, dww, dwb, wo, woH, woL, q, act);
    k_kvf<<<512, 256, 0, stream>>>(act, pw, x, wk, wv, gkv, khT, vhT);
    k_cpa<<<512, 256, 0, stream>>>(q, khT, vhT, gkv, w0, b0, w1, b1, w2, b2, outhH, outhL);
    k_out<<<256, 256, 0, stream>>>(outhH, outhL, woH, woL, bo, out);
}